// Round 12
// baseline (22.134 us; speedup 1.0000x reference)
//
#include <hip/hip_runtime.h>

#define C_IN   256
#define C_OUT  128
#define H_DIM  270
#define W_DIM  480
#define N_PTS  512
#define K_CLS  5

#define PB     16                 // points per conv block (M-tile)
#define CC     16                 // K-chunks; real K per chunk = 144, pad to 160
#define CI_PER (C_IN / CC)        // 16 ci per chunk
#define TERMS  (CI_PER * 9)       // 144 real K-terms, contiguous in conv_w per co
#define KSTEPS 5                  // ceil(144/32): kstep 4 is half real, half pad
#define JOBS   (PB * CI_PER * 3)  // 768 patch row-jobs (= 3 per thread exactly)
#define PTG_N  (N_PTS / PB)       // 32 point groups

using f32x4 = __attribute__((ext_vector_type(4))) float;
using s16x8 = __attribute__((ext_vector_type(8))) short;

// round-to-nearest-even f32 -> bf16
__device__ __forceinline__ unsigned short f2bf(float f) {
    unsigned u = __float_as_uint(f);
    return (unsigned short)((u + 0x7FFFu + ((u >> 16) & 1u)) >> 16);
}

// ---------------------------------------------------------------------------
// Kernel 1: MFMA gather-conv (R11 structure, CC=16 via K zero-padding).
// One block per (ptg, chunk): M=16 pts, N=128 co, K=144 (+16 pad). 512 blocks
// = 2 blocks/CU -> 2x the gather latency-hiding of R11's 256. 4 waves x
// 2 col-tiles. A (patch) -> bf16 -> LDS in A-frag layout; pad rows zeroed.
// B (weights) per-lane contiguous -> bf16 regs; pad frags zero. fp32 accum.
// Layouts (verified by R11 pass): A row=l&15, k=(l>>4)*8+j; B col=l&15;
// D row=(l>>4)*4+reg, col=l&15.
// ---------------------------------------------------------------------------
__global__ __launch_bounds__(256) void gemm_conv(
        const float* __restrict__ bb,       // [C_IN][H][W]
        const int*   __restrict__ centers,  // [N][2] (x, y)
        const float* __restrict__ conv_w,   // [co][ci][3][3]
        float*       __restrict__ part)     // [CC][N_PTS][C_OUT]
{
    __shared__ unsigned short pa[KSTEPS * 64 * 8];   // 5120 B, A-frag layout

    const int chunk = blockIdx.x & (CC - 1);
    const int ptg   = blockIdx.x >> 4;      // 0..31
    const int t     = threadIdx.x;
    const int l     = t & 63;
    const int w     = t >> 6;               // wave id: col-tiles {2w, 2w+1}
    const int c     = l & 15;
    const int hi    = l >> 4;

    // --- zero the A pad region (kstep 4, K-slots 16..31 -> rows 32..63) ---
    if (t < 32) {
        s16x8 z = {0, 0, 0, 0, 0, 0, 0, 0};
        *(s16x8*)&pa[(4 * 64 + 32 + t) * 8] = z;
    }

    // --- issue scattered patch loads into registers (3 row-jobs/thread) ---
    float pvv[3][3];
    #pragma unroll
    for (int jj = 0; jj < 3; ++jj) {
        const int i   = t + jj * 256;       // 0..767, exact
        const int pt  = i & 15;
        const int rem = i >> 4;             // 0..47
        const int lci = rem / 3;
        const int dy  = rem - lci * 3;
        const int n   = ptg * PB + pt;
        const int cx  = centers[2 * n];     // [0,270); cx+1 < 480 always
        const int cy  = centers[2 * n + 1];
        const int y   = cy + dy - 1;
        pvv[jj][0] = pvv[jj][1] = pvv[jj][2] = 0.f;
        if (y >= 0 && y < H_DIM) {
            const float* row = bb +
                ((size_t)(chunk * CI_PER + lci) * H_DIM + y) * W_DIM + cx;
            pvv[jj][1] = row[0];
            pvv[jj][2] = row[1];
            if (cx >= 1) pvv[jj][0] = row[-1];
        }
    }

    // --- B operand: per-lane contiguous weight runs -> bf16 frags ---
    s16x8 bfrag[2][KSTEPS];
    #pragma unroll
    for (int ct = 0; ct < 2; ++ct) {
        const int co = (2 * w + ct) * 16 + c;
        const float* base = conv_w + (size_t)co * (C_IN * 9)
                                   + chunk * TERMS + hi * 8;
        #pragma unroll
        for (int ks = 0; ks < 4; ++ks) {    // K 0..127: fully real
            const float4 lo = *(const float4*)(base + ks * 32);
            const float4 hh = *(const float4*)(base + ks * 32 + 4);
            s16x8 v;
            v[0] = (short)f2bf(lo.x); v[1] = (short)f2bf(lo.y);
            v[2] = (short)f2bf(lo.z); v[3] = (short)f2bf(lo.w);
            v[4] = (short)f2bf(hh.x); v[5] = (short)f2bf(hh.y);
            v[6] = (short)f2bf(hh.z); v[7] = (short)f2bf(hh.w);
            bfrag[ct][ks] = v;
        }
        // kstep 4: K 128..143 real (hi<2), 144..159 pad (hi>=2)
        s16x8 v4 = {0, 0, 0, 0, 0, 0, 0, 0};
        if (hi < 2) {
            const float4 lo = *(const float4*)(base + 4 * 32);
            const float4 hh = *(const float4*)(base + 4 * 32 + 4);
            v4[0] = (short)f2bf(lo.x); v4[1] = (short)f2bf(lo.y);
            v4[2] = (short)f2bf(lo.z); v4[3] = (short)f2bf(lo.w);
            v4[4] = (short)f2bf(hh.x); v4[5] = (short)f2bf(hh.y);
            v4[6] = (short)f2bf(hh.z); v4[7] = (short)f2bf(hh.w);
        }
        bfrag[ct][4] = v4;
    }

    // --- drain patch to LDS in A-fragment layout (bf16) ---
    #pragma unroll
    for (int jj = 0; jj < 3; ++jj) {
        const int i   = t + jj * 256;
        const int pt  = i & 15;
        const int rem = i >> 4;
        const int lci = rem / 3;
        const int dy  = rem - lci * 3;
        #pragma unroll
        for (int dx = 0; dx < 3; ++dx) {
            const int K  = lci * 9 + dy * 3 + dx;   // 0..143
            const int ks = K >> 5, r = K & 31;
            pa[(ks * 64 + (r >> 3) * 16 + pt) * 8 + (r & 7)] =
                f2bf(pvv[jj][dx]);
        }
    }
    __syncthreads();

    // --- MFMA loop: 5 ksteps x 2 col-tiles ---
    f32x4 acc0 = {0.f, 0.f, 0.f, 0.f};
    f32x4 acc1 = {0.f, 0.f, 0.f, 0.f};
    #pragma unroll
    for (int ks = 0; ks < KSTEPS; ++ks) {
        const s16x8 a = *(const s16x8*)&pa[(ks * 64 + l) * 8];  // lane-linear
        acc0 = __builtin_amdgcn_mfma_f32_16x16x32_bf16(a, bfrag[0][ks], acc0, 0, 0, 0);
        acc1 = __builtin_amdgcn_mfma_f32_16x16x32_bf16(a, bfrag[1][ks], acc1, 0, 0, 0);
    }

    // --- store D: row=(l>>4)*4+reg, col=l&15; 64B-coalesced over lanes ---
    #pragma unroll
    for (int reg = 0; reg < 4; ++reg) {
        const int n = ptg * PB + hi * 4 + reg;
        float* pr = part + ((size_t)chunk * N_PTS + n) * C_OUT;
        pr[(2 * w + 0) * 16 + c] = acc0[reg];
        pr[(2 * w + 1) * 16 + c] = acc1[reg];
    }
}

// ---------------------------------------------------------------------------
// Kernel 2: head. One wave per point. Lane owns co-pair (2l, 2l+1): float2
// chunk-sum (fixed order -> deterministic), bias+relu, logits/softmax/P/NLL.
// ---------------------------------------------------------------------------
__global__ __launch_bounds__(64) void head_kernel(
        const float* __restrict__ part,   // [CC][N_PTS][C_OUT]
        const float* __restrict__ conv_b, // [C_OUT]
        const float* __restrict__ fc_w,   // [K][C_OUT]
        const float* __restrict__ fc_b,   // [K]
        const float* __restrict__ L,      // [N][K]
        float*       __restrict__ P,      // [N][K]
        float*       __restrict__ loss_part) // [N]
{
    const int n    = blockIdx.x;
    const int lane = threadIdx.x;

    const float* pc = part + (size_t)n * C_OUT + 2 * lane;
    float vx = 0.f, vy = 0.f;
    #pragma unroll
    for (int cidx = 0; cidx < CC; ++cidx) {
        const float2 pp = *(const float2*)(pc + (size_t)cidx * N_PTS * C_OUT);
        vx += pp.x; vy += pp.y;
    }
    const float2 cb = *(const float2*)&conv_b[2 * lane];
    vx = fmaxf(vx + cb.x, 0.f);
    vy = fmaxf(vy + cb.y, 0.f);

    float logit[K_CLS];
    #pragma unroll
    for (int k = 0; k < K_CLS; ++k) {
        const float2 wv = *(const float2*)&fc_w[k * C_OUT + 2 * lane];
        float p = vx * wv.x + vy * wv.y;
        #pragma unroll
        for (int off = 32; off > 0; off >>= 1)
            p += __shfl_xor(p, off, 64);
        logit[k] = p + fc_b[k];
    }

    if (lane == 0) {
        float m = logit[0];
        #pragma unroll
        for (int k = 1; k < K_CLS; ++k) m = fmaxf(m, logit[k]);
        float e[K_CLS];
        float s = 0.f;
        #pragma unroll
        for (int k = 0; k < K_CLS; ++k) { e[k] = expf(logit[k] - m); s += e[k]; }
        const float inv  = 1.f / s;
        const float logs = logf(s);
        float lp = 0.f;
        #pragma unroll
        for (int k = 0; k < K_CLS; ++k) {
            P[n * K_CLS + k] = e[k] * inv;
            lp -= L[n * K_CLS + k] * ((logit[k] - m) - logs);
        }
        loss_part[n] = lp;
    }
}

// ---------------------------------------------------------------------------
// Kernel 3: deterministic loss reduction (one block, no atomics).
// ---------------------------------------------------------------------------
__global__ __launch_bounds__(512) void reduce_loss(
        const float* __restrict__ loss_part, float* __restrict__ out) {
    __shared__ float sh[N_PTS];
    const int t = threadIdx.x;
    sh[t] = loss_part[t];
    __syncthreads();
    for (int s = N_PTS / 2; s > 0; s >>= 1) {
        if (t < s) sh[t] += sh[t + s];
        __syncthreads();
    }
    if (t == 0) out[0] = sh[0];
}

// ---------------------------------------------------------------------------
extern "C" void kernel_launch(void* const* d_in, const int* in_sizes, int n_in,
                              void* d_out, int out_size, void* d_ws, size_t ws_size,
                              hipStream_t stream) {
    const float* bb      = (const float*)d_in[0];   // backbone_map
    const int*   centers = (const int*)  d_in[1];
    const float* L       = (const float*)d_in[2];
    const float* conv_w  = (const float*)d_in[3];
    const float* conv_b  = (const float*)d_in[4];
    const float* fc_w    = (const float*)d_in[5];
    const float* fc_b    = (const float*)d_in[6];

    float* out = (float*)d_out;            // P: [0, 2560), loss: [2560]

    // workspace (floats): part 16*512*128 (4.2 MB) + loss_part
    float* part      = (float*)d_ws;
    float* loss_part = part + (size_t)CC * N_PTS * C_OUT;

    gemm_conv<<<PTG_N * CC, 256, 0, stream>>>(bb, centers, conv_w, part);
    head_kernel<<<N_PTS, 64, 0, stream>>>(part, conv_b, fc_w, fc_b, L, out,
                                          loss_part);
    reduce_loss<<<1, N_PTS, 0, stream>>>(loss_part, out + N_PTS * K_CLS);
}